// Round 1
// baseline (224.887 us; speedup 1.0000x reference)
//
#include <hip/hip_runtime.h>

// Native 4-float vector (clang ext_vector_type) — required for
// __builtin_nontemporal_load/store (HIP's float4 class is rejected).
typedef float nfloat4 __attribute__((ext_vector_type(4)));

// One 64-lane wave per (b,c) slice of 32x32 fp32.
// Block = 256 threads = 4 independent waves; no LDS, no block sync.
// Grid-stride over slices with a capped grid (2048 blocks = 8 blocks/CU
// resident): 32768 slices = 2048 blocks * 4 waves * 4 iterations exactly.
//
// Per slice: lane i loads float4s at {i, i+64, i+128, i+192} (16B/lane,
// 1 KiB per wave instruction), wave-reduces argmax (first-occurrence
// tiebreak), applies drop-block mask, stores. All global traffic is
// nontemporal (pure stream; the harness's 1 GB/iter poison fills flush
// L3 anyway, so there is no cross-iteration reuse to cache).
//
// Key change vs previous version: the slice index is forced wave-uniform
// via readfirstlane, so x/out bases live in SGPRs (global_load_dwordx4
// with scalar base) and the T[slice] fetch becomes an s_load. The branch
// on sel then resolves on lgkmcnt instead of forcing s_waitcnt vmcnt(0),
// letting the copy path pipeline its stores at vmcnt(3/2/1/0).
__global__ __launch_bounds__(256) void drop_block_kernel(
    const float* __restrict__ x,
    const int* __restrict__ T,
    const int* __restrict__ dropb,
    float* __restrict__ out,
    int n_slices) {
  const int lane = threadIdx.x & 63;
  const int wave_in_blk = threadIdx.x >> 6;
  const int wave_stride = gridDim.x << 2;  // total waves in grid
  const int half = dropb[0] >> 1;          // floor(drop_block/2), uniform

  for (int slice = (blockIdx.x << 2) + wave_in_blk; slice < n_slices;
       slice += wave_stride) {
    // Wave-uniform slice index -> SGPR bases, scalar T load.
    const int us = __builtin_amdgcn_readfirstlane(slice);
    const nfloat4* __restrict__ x4 = (const nfloat4*)x + (size_t)us * 256;
    nfloat4* __restrict__ o4 = (nfloat4*)out + (size_t)us * 256;

    // 16 floats per lane, held in registers the whole time (single pass).
    nfloat4 v0 = __builtin_nontemporal_load(&x4[lane]);
    nfloat4 v1 = __builtin_nontemporal_load(&x4[lane + 64]);
    nfloat4 v2 = __builtin_nontemporal_load(&x4[lane + 128]);
    nfloat4 v3 = __builtin_nontemporal_load(&x4[lane + 192]);

    const int sel = T[us];  // uniform address -> s_load (lgkmcnt path)

    if (!sel) {
      // wave-uniform passthrough; stores pipeline per-load on vmcnt
      __builtin_nontemporal_store(v0, &o4[lane]);
      __builtin_nontemporal_store(v1, &o4[lane + 64]);
      __builtin_nontemporal_store(v2, &o4[lane + 128]);
      __builtin_nontemporal_store(v3, &o4[lane + 192]);
      continue;
    }

    // ---- in-lane argmax: 4 independent chunk chains (ILP), ordered merge.
    // Strict '>' with ascending-index evaluation => first occurrence wins.
#define ARG4(vec, base, BV, BI)                         \
    float BV = vec.x; int BI = (base);                  \
    if (vec.y > BV) { BV = vec.y; BI = (base) + 1; }    \
    if (vec.z > BV) { BV = vec.z; BI = (base) + 2; }    \
    if (vec.w > BV) { BV = vec.w; BI = (base) + 3; }

    ARG4(v0, lane * 4, bv0, bi0)
    ARG4(v1, (lane + 64) * 4, bv1, bi1)
    ARG4(v2, (lane + 128) * 4, bv2, bi2)
    ARG4(v3, (lane + 192) * 4, bv3, bi3)
#undef ARG4

    // ordered merge (chunk 0 has the lowest indices, keep strict '>')
    float bv = bv0; int bi = bi0;
    if (bv1 > bv) { bv = bv1; bi = bi1; }
    if (bv2 > bv) { bv = bv2; bi = bi2; }
    if (bv3 > bv) { bv = bv3; bi = bi3; }

    // ---- cross-lane butterfly reduce (64-wide), lowest-index tiebreak
    for (int off = 32; off > 0; off >>= 1) {
      float ov = __shfl_xor(bv, off, 64);
      int oi = __shfl_xor(bi, off, 64);
      if (ov > bv || (ov == bv && oi < bi)) { bv = ov; bi = oi; }
    }

    // ---- box + normalization (exact: sum(S) is an integer)
    const int mh = bi >> 5;
    const int mw = bi & 31;
    int h1 = mh - half; h1 = h1 < 0 ? 0 : (h1 > 31 ? 31 : h1);
    int h2 = mh + half; h2 = h2 < 0 ? 0 : (h2 > 31 ? 31 : h2);
    int w1 = mw - half; w1 = w1 < 0 ? 0 : (w1 > 31 ? 31 : w1);
    int w2 = mw + half; w2 = w2 < 0 ? 0 : (w2 > 31 ? 31 : w2);
    const int area = (h2 - h1 + 1) * (w2 - w1 + 1);
    const float lam = 1024.0f / (float)(1024 - area);

    // ---- apply mask + scale, store (nontemporal)
#define APPLY(vec, base)                                                \
    do {                                                                \
      nfloat4 _r;                                                       \
      {                                                                 \
        int _i = (base);                                                \
        int _r0 = _i >> 5, _c0 = _i & 31;                               \
        bool _in = (_r0 >= h1) & (_r0 <= h2) & (_c0 >= w1) & (_c0 <= w2); \
        _r.x = _in ? 0.0f : vec.x * lam;                                \
        _c0 = (_i + 1) & 31; _r0 = (_i + 1) >> 5;                       \
        _in = (_r0 >= h1) & (_r0 <= h2) & (_c0 >= w1) & (_c0 <= w2);    \
        _r.y = _in ? 0.0f : vec.y * lam;                                \
        _c0 = (_i + 2) & 31; _r0 = (_i + 2) >> 5;                       \
        _in = (_r0 >= h1) & (_r0 <= h2) & (_c0 >= w1) & (_c0 <= w2);    \
        _r.z = _in ? 0.0f : vec.z * lam;                                \
        _c0 = (_i + 3) & 31; _r0 = (_i + 3) >> 5;                       \
        _in = (_r0 >= h1) & (_r0 <= h2) & (_c0 >= w1) & (_c0 <= w2);    \
        _r.w = _in ? 0.0f : vec.w * lam;                                \
      }                                                                 \
      __builtin_nontemporal_store(_r, &o4[(base) >> 2]);                \
    } while (0)

    APPLY(v0, lane * 4);
    APPLY(v1, (lane + 64) * 4);
    APPLY(v2, (lane + 128) * 4);
    APPLY(v3, (lane + 192) * 4);
#undef APPLY
  }
}

extern "C" void kernel_launch(void* const* d_in, const int* in_sizes, int n_in,
                              void* d_out, int out_size, void* d_ws, size_t ws_size,
                              hipStream_t stream) {
  const float* x = (const float*)d_in[0];
  const int* T = (const int*)d_in[1];
  const int* dropb = (const int*)d_in[2];
  float* out = (float*)d_out;

  const int n_slices = in_sizes[1];  // 128*256 = 32768
  int blocks = (n_slices + 3) / 4;
  if (blocks > 2048) blocks = 2048;  // 8 blocks/CU resident; grid-stride rest
  drop_block_kernel<<<blocks, 256, 0, stream>>>(x, T, dropb, out, n_slices);
}